// Round 9
// baseline (725.930 us; speedup 1.0000x reference)
//
#include <hip/hip_runtime.h>
#include <hip/hip_bf16.h>
#include <math.h>

// ---------------------------------------------------------------------------
// Gemma audio layer, round 8: round 7 with the attention output-store bug
// fixed (loop covered only d<64; now 4 x 512 slots = full 128x128 tile).
//  GEMM: conflict-free swizzle + ring-4 + pipelined fragment reads (1 ahead).
//  Attn: fast exact tanh + coalesced LDS-staged output stores.
// ---------------------------------------------------------------------------

#define NH_    12
#define HD_    128
#define H_     1536
#define B_     4
#define S_     4096
#define CHUNK_ 128
#define CTX_   255
#define NB_    32
#define QKVW_  4608

typedef unsigned short u16;
typedef short bf16x8 __attribute__((ext_vector_type(8)));
typedef float f32x4 __attribute__((ext_vector_type(4)));

static constexpr float Q_SCALE_F = (float)(0.08838834764831845 / 0.6931471805599453);
static constexpr float K_SCALE_F = (float)(1.3132616875182228 / 0.6931471805599453);

__device__ __forceinline__ u16 f2bf(float f) {
    __hip_bfloat16 h = __float2bfloat16(f);
    return __builtin_bit_cast(u16, h);
}
__device__ __forceinline__ float bf2f(u16 u) {
    unsigned int t = ((unsigned int)u) << 16;
    return __builtin_bit_cast(float, t);
}
__device__ __forceinline__ float fast_tanh(float t) {
    // exact: tanh(t) = sign(t) * (1-u)/(1+u), u = e^{-2|t|}; u<=1, no overflow
    float u = __expf(-2.f * fabsf(t));
    float r = (1.f - u) / (1.f + u);
    return (t < 0.f) ? -r : r;
}

__device__ __forceinline__ void gload_lds16(const u16* src_global, u16* dst_lds) {
    __builtin_amdgcn_global_load_lds(
        (const __attribute__((address_space(1))) unsigned int*)src_global,
        (__attribute__((address_space(3))) unsigned int*)dst_lds,
        16, 0, 0);
}

// ---------------------------------------------------------------------------
// fp32 -> bf16 conversion with optional scaling / zero-fill.
// ---------------------------------------------------------------------------
__global__ __launch_bounds__(256)
void conv_bf16(const float* __restrict__ src, long long base,
               u16* __restrict__ dst, long long n,
               long long zero_below, long long zero_from,
               int mode, const float* __restrict__ pds, int ncols)
{
    long long i = ((long long)blockIdx.x * 256 + threadIdx.x) * 4;
    if (i >= n) return;
    float4 v = make_float4(0.f, 0.f, 0.f, 0.f);
    if (i >= zero_below && i < zero_from)
        v = *(const float4*)(src + base + i);
    float s = 1.f;
    if (mode == 1) {
        int row = (int)(i / ncols);
        float x = pds[row & 127];
        float sp = (x > 20.f) ? x : log1pf(__expf(x));
        s = Q_SCALE_F * sp;
    } else if (mode == 2) {
        s = K_SCALE_F;
    }
    ushort4 o = make_ushort4(f2bf(v.x * s), f2bf(v.y * s), f2bf(v.z * s), f2bf(v.w * s));
    *(ushort4*)(dst + i) = o;
}

// ---------------------------------------------------------------------------
// bf16 GEMM  C[M,N] = A[M,K] @ B[N,K]^T  (row-major bf16, K mult of 128,
// M,N mult of 128). OUTB: 1 -> bf16 C (LDS-staged coalesced), 0 -> fp32 C.
// 128x128 tile, 4 waves, 16x16x32 MFMA.
// LDS tile: [row][4 x 16B slots], phys slot = log_slot ^ ((row>>1)&3)
//   (conflict-free ds_read_b128: 2 lanes/bank). gload_lds dests LINEAR;
//   global SOURCE pre-swizzled (both-sides-or-neither).
// K-loop: ring-4, stage 2 ahead, frag reads pipelined 1 iter ahead:
//   ITER(t): [stage(t+2)] vmcnt(4) barrier; read frags(t+1); MFMA frags(t).
// ---------------------------------------------------------------------------
#define STAGE(kt, bufc) do {                                                   \
    const int _ko = (kt) << 5;                                                 \
    gload_lds16(srcA[0] + _ko, lds + (bufc) * 4096 + pbase[0]);                \
    gload_lds16(srcA[1] + _ko, lds + (bufc) * 4096 + pbase[1]);                \
    gload_lds16(srcB[0] + _ko, lds + 16384 + (bufc) * 4096 + pbase[0]);        \
    gload_lds16(srcB[1] + _ko, lds + 16384 + (bufc) * 4096 + pbase[1]);        \
} while (0)

#define READF(afX, bfX, b) do {                                                \
    _Pragma("unroll")                                                          \
    for (int m = 0; m < 4; ++m)                                                \
        afX[m] = *(const bf16x8*)&lds[(b) * 4096 + (wr + m * 16 + lr) * 32 + sw8]; \
    _Pragma("unroll")                                                          \
    for (int n = 0; n < 4; ++n)                                                \
        bfX[n] = *(const bf16x8*)&lds[16384 + (b) * 4096 + (wc + n * 16 + lr) * 32 + sw8]; \
} while (0)

#define MFMA16(afX, bfX) do {                                                  \
    __builtin_amdgcn_s_setprio(1);                                             \
    _Pragma("unroll")                                                          \
    for (int m = 0; m < 4; ++m)                                                \
        _Pragma("unroll")                                                      \
        for (int n = 0; n < 4; ++n)                                            \
            acc[m][n] = __builtin_amdgcn_mfma_f32_16x16x32_bf16(afX[m], bfX[n], acc[m][n], 0, 0, 0); \
    __builtin_amdgcn_s_setprio(0);                                             \
} while (0)

#define ITER(t, b, afC, bfC, afN, bfN) do {                                    \
    if ((t) + 2 < nk) {                                                        \
        STAGE((t) + 2, ((b) + 2) & 3);                                         \
        asm volatile("s_waitcnt vmcnt(4)" ::: "memory");                       \
    } else {                                                                   \
        asm volatile("s_waitcnt vmcnt(0)" ::: "memory");                       \
    }                                                                          \
    __builtin_amdgcn_s_barrier();                                              \
    if ((t) + 1 < nk) READF(afN, bfN, ((b) + 1) & 3);                          \
    MFMA16(afC, bfC);                                                          \
} while (0)

template<int OUTB>
__global__ __launch_bounds__(256)
void gemm_bt(const u16* __restrict__ A, const u16* __restrict__ B,
             void* __restrict__ Cp, int M, int N, int K, int ldc)
{
    // 64 KB: A ring 4x8KB at [0..16384) u16, B ring at [16384..32768).
    // Epilogue cbuf aliases [0..8704) u16 -- disjoint from buf3 (last reads).
    __shared__ __align__(16) u16 lds[32768];

    const int tid = threadIdx.x;
    const int w = tid >> 6, l = tid & 63;
    const int lr = l & 15, lg = l >> 4;
    const int bm = blockIdx.y * 128, bn = blockIdx.x * 128;
    const int wr = (w >> 1) * 64, wc = (w & 1) * 64;

    // conflict-free fragment slot: log slot lg at row ..+lr -> phys lg^((lr>>1)&3)
    const int sw8 = (lg ^ ((lr >> 1) & 3)) * 8;

    // staging: chunk c: linear 16B slot p; dest row p>>2, phys slot p&3;
    // source logical slot = (p&3) ^ ((row>>1)&3)
    const u16* srcA[2];
    const u16* srcB[2];
    int pbase[2];
#pragma unroll
    for (int c = 0; c < 2; ++c) {
        const int p = (w * 2 + c) * 64 + l;
        const int row = p >> 2;
        const int s_log = (p & 3) ^ ((row >> 1) & 3);
        pbase[c] = p * 8;
        srcA[c] = A + (size_t)(bm + row) * K + s_log * 8;
        srcB[c] = B + (size_t)(bn + row) * K + s_log * 8;
    }

    f32x4 acc[4][4];
#pragma unroll
    for (int m = 0; m < 4; ++m)
#pragma unroll
        for (int n = 0; n < 4; ++n) acc[m][n] = (f32x4){0.f, 0.f, 0.f, 0.f};

    const int nk = K >> 5;                    // K/32; K%128==0 -> nk%4==0
    bf16x8 af0[4], bf0[4], af1[4], bf1[4];

    STAGE(0, 0);
    STAGE(1, 1);
    asm volatile("s_waitcnt vmcnt(4)" ::: "memory");   // stage(0) landed
    __builtin_amdgcn_s_barrier();
    READF(af0, bf0, 0);

    for (int t0 = 0; t0 < nk; t0 += 4) {
        ITER(t0 + 0, 0, af0, bf0, af1, bf1);
        ITER(t0 + 1, 1, af1, bf1, af0, bf0);
        ITER(t0 + 2, 2, af0, bf0, af1, bf1);
        ITER(t0 + 3, 3, af1, bf1, af0, bf0);
    }

    // C/D layout: col = lane&15 (lr), row = lg*4 + r
    if (OUTB) {
#pragma unroll
        for (int h = 0; h < 2; ++h) {
            if (wr == h * 64) {
#pragma unroll
                for (int m = 0; m < 4; ++m)
#pragma unroll
                    for (int n = 0; n < 4; ++n)
#pragma unroll
                        for (int r = 0; r < 4; ++r)
                            lds[(m * 16 + lg * 4 + r) * 136 + wc + n * 16 + lr] =
                                f2bf(acc[m][n][r]);
            }
            __syncthreads();
#pragma unroll
            for (int it = 0; it < 4; ++it) {
                const int sid = it * 256 + tid;
                const int row = sid >> 4, sl = sid & 15;
                int4 val = *(const int4*)&lds[row * 136 + sl * 8];
                *(int4*)((u16*)Cp + (size_t)(bm + h * 64 + row) * ldc + bn + sl * 8) = val;
            }
            __syncthreads();
        }
    } else {
#pragma unroll
        for (int m = 0; m < 4; ++m)
#pragma unroll
            for (int n = 0; n < 4; ++n)
#pragma unroll
                for (int r = 0; r < 4; ++r) {
                    const int row = bm + wr + m * 16 + lg * 4 + r;
                    const int col = bn + wc + n * 16 + lr;
                    ((float*)Cp)[(size_t)row * ldc + col] = acc[m][n][r];
                }
    }
}

// ---------------------------------------------------------------------------
// MFMA attention: round-2 structure + fast_tanh + coalesced output stores.
// ---------------------------------------------------------------------------
__global__ __launch_bounds__(512)
void attn_mfma(const u16* __restrict__ qkv, const u16* __restrict__ relk,
               u16* __restrict__ attn_out)
{
    __shared__ __align__(16) u16 kv_s[256 * 128];   // relk -> k_ctx -> V^T -> out
    __shared__ __align__(16) u16 g_s[128 * 264];    // G -> P

    const int ln = blockIdx.x, h = blockIdx.y;
    const int tid = threadIdx.x;
    const int w = tid >> 6, l = tid & 63;
    const int lr = l & 15, lg = l >> 4;
    const size_t qrow0 = (size_t)(ln + 1) * 128;

    bf16x8 qa[4];
    {
        const u16* qp = qkv + (qrow0 + w * 16 + lr) * QKVW_ + h * HD_ + lg * 8;
#pragma unroll
        for (int kk = 0; kk < 4; ++kk) qa[kk] = *(const bf16x8*)(qp + kk * 32);
    }

#pragma unroll
    for (int it = 0; it < 8; ++it) {
        int sid = it * 512 + tid;
        int row = sid >> 4, sl = sid & 15;
        int4 v = *(const int4*)(relk + (size_t)row * H_ + h * HD_ + sl * 8);
        *(int4*)&kv_s[row * 128 + (((sl ^ (row & 15)) << 3))] = v;
    }
    __syncthreads();

    f32x4 sacc[16];
#pragma unroll
    for (int n = 0; n < 16; ++n) sacc[n] = (f32x4){0.f, 0.f, 0.f, 0.f};
#pragma unroll
    for (int n = 0; n < 16; ++n)
#pragma unroll
        for (int kk = 0; kk < 4; ++kk) {
            int row = n * 16 + lr;
            int sl = kk * 4 + lg;
            bf16x8 bfrag = *(const bf16x8*)&kv_s[row * 128 + ((sl ^ (row & 15)) << 3)];
            sacc[n] = __builtin_amdgcn_mfma_f32_16x16x32_bf16(qa[kk], bfrag, sacc[n], 0, 0, 0);
        }

    const int c = w * 16 + lg * 4;
#pragma unroll
    for (int n = 0; n < 16; ++n)
#pragma unroll
        for (int r = 0; r < 4; ++r)
            g_s[(c + r) * 264 + n * 16 + lr] = f2bf(sacc[n][r]);
    __syncthreads();

#pragma unroll
    for (int it = 0; it < 8; ++it) {
        int sid = it * 512 + tid;
        int row = sid >> 4, sl = sid & 15;
        int4 v = make_int4(0, 0, 0, 0);
        if (row < 255)
            v = *(const int4*)(qkv + (size_t)(ln * 128 + 1 + row) * QKVW_ + H_ + h * HD_ + sl * 8);
        *(int4*)&kv_s[row * 128 + ((sl ^ (row & 15)) << 3)] = v;
    }
    __syncthreads();

#pragma unroll
    for (int n = 0; n < 16; ++n) sacc[n] = (f32x4){0.f, 0.f, 0.f, 0.f};
#pragma unroll
    for (int n = 0; n < 16; ++n)
#pragma unroll
        for (int kk = 0; kk < 4; ++kk) {
            int row = n * 16 + lr;
            int sl = kk * 4 + lg;
            bf16x8 bfrag = *(const bf16x8*)&kv_s[row * 128 + ((sl ^ (row & 15)) << 3)];
            sacc[n] = __builtin_amdgcn_mfma_f32_16x16x32_bf16(qa[kk], bfrag, sacc[n], 0, 0, 0);
        }

#pragma unroll
    for (int n = 0; n < 16; ++n)
#pragma unroll
        for (int r = 0; r < 4; ++r) {
            int cc = c + r;
            int x = n * 16 + lr;
            float val;
            if (x == 255) {
                val = -1e30f;
            } else {
                int dx = x - cc;
                u16 bdu = (dx >= 0) ? g_s[cc * 264 + dx]
                                    : g_s[(cc - 1) * 264 + dx + 256];
                float t = (sacc[n][r] + bf2f(bdu)) * (1.f / 50.f);
                val = 50.f * fast_tanh(t);
            }
            sacc[n][r] = val;
        }

#pragma unroll
    for (int r = 0; r < 4; ++r) {
        float m = -1e30f;
#pragma unroll
        for (int n = 0; n < 16; ++n) m = fmaxf(m, sacc[n][r]);
#pragma unroll
        for (int off = 1; off < 16; off <<= 1) m = fmaxf(m, __shfl_xor(m, off, 16));
        float s = 0.f;
#pragma unroll
        for (int n = 0; n < 16; ++n) {
            float e = __expf(sacc[n][r] - m);
            sacc[n][r] = e;
            s += e;
        }
#pragma unroll
        for (int off = 1; off < 16; off <<= 1) s += __shfl_xor(s, off, 16);
        float inv = 1.f / s;
#pragma unroll
        for (int n = 0; n < 16; ++n) sacc[n][r] *= inv;
    }
    __syncthreads();

#pragma unroll
    for (int n = 0; n < 16; ++n)
#pragma unroll
        for (int r = 0; r < 4; ++r)
            g_s[(c + r) * 264 + n * 16 + lr] = f2bf(sacc[n][r]);

#pragma unroll
    for (int it = 0; it < 8; ++it) {
        int ti = it * 512 + tid;
        int x = ti >> 4, dg = ti & 15;
        int4 vv = make_int4(0, 0, 0, 0);
        if (x < 255)
            vv = *(const int4*)(qkv + (size_t)(ln * 128 + 1 + x) * QKVW_ + 2 * H_ + h * HD_ + dg * 8);
        const u16* vs = (const u16*)&vv;
#pragma unroll
        for (int i = 0; i < 8; ++i) {
            int d = dg * 8 + i;
            int sl = x >> 3, xo = x & 7;
            kv_s[d * 256 + (((sl ^ (d & 15)) << 3) + xo)] = vs[i];
        }
    }
    __syncthreads();

    f32x4 oacc[8];
#pragma unroll
    for (int n = 0; n < 8; ++n) oacc[n] = (f32x4){0.f, 0.f, 0.f, 0.f};
#pragma unroll
    for (int kk = 0; kk < 8; ++kk) {
        int prow = w * 16 + lr;
        bf16x8 pa = *(const bf16x8*)&g_s[prow * 264 + kk * 32 + lg * 8];
#pragma unroll
        for (int n = 0; n < 8; ++n) {
            int d = n * 16 + lr;
            int sl = kk * 4 + lg;
            bf16x8 vb = *(const bf16x8*)&kv_s[d * 256 + ((sl ^ (d & 15)) << 3)];
            oacc[n] = __builtin_amdgcn_mfma_f32_16x16x32_bf16(pa, vb, oacc[n], 0, 0, 0);
        }
    }

    // ---- coalesced output: stage into kv_s [128 rows][136], then 16B stores
    __syncthreads();   // all PV reads of kv_s complete
#pragma unroll
    for (int n = 0; n < 8; ++n)
#pragma unroll
        for (int r = 0; r < 4; ++r)
            kv_s[(c + r) * 136 + n * 16 + lr] = f2bf(oacc[n][r]);
    __syncthreads();
#pragma unroll
    for (int it = 0; it < 4; ++it) {
        const int sid = it * 512 + tid;        // 0..2047: full 128x128 tile
        const int row = sid >> 4, sl = sid & 15;
        int4 val = *(const int4*)&kv_s[row * 136 + sl * 8];
        *(int4*)(attn_out + (size_t)(ln * 128 + row) * H_ + h * HD_ + sl * 8) = val;
    }
}

// ---------------------------------------------------------------------------
extern "C" void kernel_launch(void* const* d_in, const int* in_sizes, int n_in,
                              void* d_out, int out_size, void* d_ws, size_t ws_size,
                              hipStream_t stream)
{
    (void)in_sizes; (void)n_in; (void)out_size;

    const float* hs    = (const float*)d_in[0];
    const float* pos   = (const float*)d_in[1];
    const float* Wq    = (const float*)d_in[2];
    const float* Wk    = (const float*)d_in[3];
    const float* Wv    = (const float*)d_in[4];
    const float* Wrel  = (const float*)d_in[5];
    const float* Wpost = (const float*)d_in[6];
    const float* pds   = (const float*)d_in[7];
    float* out = (float*)d_out;

    const long long WW = (long long)H_ * H_;
    const long long POSN = 256LL * H_;
    const long long fixed_elems = (long long)QKVW_ * H_ + 2 * WW + 2 * POSN;

    int G = 0;
    const int cand[6] = {32, 16, 8, 4, 2, 1};
    for (int ci = 0; ci < 6; ++ci) {
        int g = cand[ci];
        long long seg_elems = (long long)(g + 1) * 128 * (H_ + QKVW_)
                            + (long long)g * 128 * H_;
        if ((fixed_elems + seg_elems) * 2 <= (long long)ws_size) { G = g; break; }
    }
    if (G == 0) return;

    u16* wqkvb  = (u16*)d_ws;
    u16* wpostb = wqkvb + (long long)QKVW_ * H_;
    u16* wrelb  = wpostb + WW;
    u16* posb   = wrelb + WW;
    u16* relkb  = posb + POSN;
    u16* hsb    = relkb + POSN;
    u16* qkvb   = hsb + (long long)(G + 1) * 128 * H_;
    u16* attb   = qkvb + (long long)(G + 1) * 128 * QKVW_;

    dim3 blk(256);
    const long long BIG = 1LL << 60;

    conv_bf16<<<dim3(WW / 1024), blk, 0, stream>>>(Wq, 0, wqkvb,          WW, 0, BIG, 1, pds, H_);
    conv_bf16<<<dim3(WW / 1024), blk, 0, stream>>>(Wk, 0, wqkvb + WW,     WW, 0, BIG, 2, nullptr, H_);
    conv_bf16<<<dim3(WW / 1024), blk, 0, stream>>>(Wv, 0, wqkvb + 2 * WW, WW, 0, BIG, 0, nullptr, H_);
    conv_bf16<<<dim3(WW / 1024), blk, 0, stream>>>(Wpost, 0, wpostb,      WW, 0, BIG, 0, nullptr, H_);
    conv_bf16<<<dim3(WW / 1024), blk, 0, stream>>>(Wrel, 0, wrelb,        WW, 0, BIG, 0, nullptr, H_);
    conv_bf16<<<dim3(POSN / 1024), blk, 0, stream>>>(pos, 0, posb, POSN, 0, 255LL * H_, 0, nullptr, H_);

    gemm_bt<1><<<dim3(H_ / 128, 2), blk, 0, stream>>>(posb, wrelb, relkb, 256, H_, H_, H_);

    for (int b = 0; b < B_; ++b) {
        for (int n0 = 0; n0 < NB_; n0 += G) {
            const int Mh = (G + 1) * 128;
            const long long hs_base = ((long long)b * S_ + (long long)(n0 - 1) * CHUNK_) * H_;
            const long long zb = (n0 == 0) ? (long long)CHUNK_ * H_ : 0;
            const long long hn = (long long)Mh * H_;

            conv_bf16<<<dim3(hn / 1024), blk, 0, stream>>>(hs, hs_base, hsb, hn, zb, BIG, 0, nullptr, H_);

            gemm_bt<1><<<dim3(QKVW_ / 128, Mh / 128), blk, 0, stream>>>(
                hsb, wqkvb, qkvb, Mh, QKVW_, H_, QKVW_);

            attn_mfma<<<dim3(G, NH_), dim3(512), 0, stream>>>(qkvb, relkb, attb);

            gemm_bt<0><<<dim3(H_ / 128, G), blk, 0, stream>>>(
                attb, wpostb, out + ((long long)b * S_ + (long long)n0 * CHUNK_) * H_,
                G * CHUNK_, H_, H_, H_);
        }
    }
}